// Round 1
// 397.762 us; speedup vs baseline: 1.0702x; 1.0702x over previous
//
#include <hip/hip_runtime.h>
#include <hip/hip_bf16.h>

// ROUND 13: LDS XOR-swizzle (T2 / m214-style) on all [*][64] bf16 tiles.
// Contract (R11 PASS, absmax 4.9e-4): inputs fp32 dict-order, output fp32,
// shown interleaved split (head h owns qkv channels [h*192,(h+1)*192)),
// scale 1/8, out = att_v @ W_out^T + b_out. ws: qkv [b*16+h][t][192] bf16
// (48 MiB, in-place q-slot for att_v — audited R6-R11).
// R13 change: every LDS tile with 128-byte rows ([R][64] u16) had 16-phase
// bank serialization on ds_read_b128 fragment reads (16 rows x same 16B slot
// -> same 4-bank group; floor is 8 phases). Fix: bijective per-row slot
// swizzle  idx = row*64 + ((slot ^ (row&7))<<3)  on BOTH writes and reads of
// Ks/Vts/Ps (attn) and As/Bs (gemm). Pure address permutation — no numeric
// change. rocprof R12: SQ_LDS_BANK_CONFLICT=3.99e7 on attn (~28% of cycles).

typedef unsigned short u16;
typedef short bf16x8 __attribute__((ext_vector_type(8)));   // 8 bf16 = 4 VGPRs
typedef float floatx4 __attribute__((ext_vector_type(4)));

#define BB 4
#define TT 2048
#define CC 1024
#define HH 16

__device__ __forceinline__ float bf2f(u16 u) {
    union { unsigned v; float f; } x; x.v = ((unsigned)u) << 16; return x.f;
}
__device__ __forceinline__ u16 f2bf(float f) {
    union { float f; unsigned v; } x; x.f = f;
    unsigned r = x.v + 0x7fffu + ((x.v >> 16) & 1u);   // RNE
    return (u16)(r >> 16);
}
// 8 contiguous fp32 -> bf16x8 (two 16B loads + RNE pack)
__device__ __forceinline__ bf16x8 cvt8(const float* p) {
    floatx4 a = *(const floatx4*)p;
    floatx4 b = *(const floatx4*)(p + 4);
    bf16x8 r;
    r[0] = (short)f2bf(a[0]); r[1] = (short)f2bf(a[1]);
    r[2] = (short)f2bf(a[2]); r[3] = (short)f2bf(a[3]);
    r[4] = (short)f2bf(b[0]); r[5] = (short)f2bf(b[1]);
    r[6] = (short)f2bf(b[2]); r[7] = (short)f2bf(b[3]);
    return r;
}
// XOR-swizzled u16 index into a [R][64] u16 tile for a 16B slot (slot=0..7).
// Spreads the 8 slots of a 128B row across bank groups per 8-row stripe.
__device__ __forceinline__ int sw8(int row, int slot) {
    return row * 64 + (((slot ^ (row & 7)) & 7) << 3);
}

// ---------------- GEMM: C = A @ B^T + bias ----------------------------------------
// 128x128 tile, BK=64, 256 threads = 4 waves (2x2), each wave 64x64 via 4x4 MFMA.
// SCATTER=1: C -> qkv ws scatter (bf16), shown split h=col/192.
// SCATTER=0: C -> fp32 out, A gathered from q-slots (QSLOT=1).
template <int SCATTER, int QSLOT>
__global__ __launch_bounds__(256) void gemm_bt(const void* __restrict__ Av,
                                               const float* __restrict__ Bw,
                                               const float* __restrict__ bias,
                                               void* __restrict__ Cv,
                                               int K, int N) {
    __shared__ u16 As[128 * 64];   // 16 KB
    __shared__ u16 Bs[128 * 64];   // 16 KB

    const int tid  = threadIdx.x;
    const int lane = tid & 63;
    const int wave = tid >> 6;
    const int quad = lane >> 4;
    const int l15  = lane & 15;
    const int wm   = (wave >> 1) * 64;
    const int wn   = (wave & 1) * 64;
    const int blockM = blockIdx.y * 128;
    const int blockN = blockIdx.x * 128;

    floatx4 acc[4][4];
#pragma unroll
    for (int i = 0; i < 4; i++)
#pragma unroll
        for (int j = 0; j < 4; j++) acc[i][j] = (floatx4){0.f, 0.f, 0.f, 0.f};

    const int srow = lane >> 3;        // 0..7: row within an 8-row chunk
    const int scol = (lane & 7) * 8;   // 0..56: col; srow*64+scol == lane*8

    for (int k0 = 0; k0 < K; k0 += 64) {
        bf16x8 at[4], bt[4];
#pragma unroll
        for (int i = 0; i < 4; i++) {
            const int row = blockM + (i * 4 + wave) * 8 + srow;
            if (QSLOT) {   // A = att_v in q-slots: k0 selects head (BK==hs==64)
                const int b = row >> 11, t = row & 2047, h = k0 >> 6;
                at[i] = *(const bf16x8*)((const u16*)Av
                         + ((size_t)((b * HH + h) * TT + t)) * 192 + scol);
            } else {       // A = x, fp32 -> bf16
                at[i] = cvt8((const float*)Av + (size_t)row * K + k0 + scol);
            }
        }
#pragma unroll
        for (int i = 0; i < 4; i++)
            bt[i] = cvt8(Bw + (size_t)(blockN + (i * 4 + wave) * 8 + srow) * K + k0 + scol);

        __syncthreads();   // prev iteration's LDS readers done
#pragma unroll
        for (int i = 0; i < 4; i++)
            *(bf16x8*)&As[sw8((i * 4 + wave) * 8 + srow, lane & 7)] = at[i];
#pragma unroll
        for (int i = 0; i < 4; i++)
            *(bf16x8*)&Bs[sw8((i * 4 + wave) * 8 + srow, lane & 7)] = bt[i];
        __syncthreads();

#pragma unroll
        for (int ks = 0; ks < 2; ks++) {
            const int slot = ks * 4 + quad;   // 16B slot index of ko
            bf16x8 af[4], bfr[4];
#pragma unroll
            for (int mi = 0; mi < 4; mi++)
                af[mi] = *(const bf16x8*)&As[sw8(wm + mi * 16 + l15, slot)];
#pragma unroll
            for (int ni = 0; ni < 4; ni++)
                bfr[ni] = *(const bf16x8*)&Bs[sw8(wn + ni * 16 + l15, slot)];
#pragma unroll
            for (int mi = 0; mi < 4; mi++)
#pragma unroll
                for (int ni = 0; ni < 4; ni++)
                    acc[mi][ni] = __builtin_amdgcn_mfma_f32_16x16x32_bf16(
                        af[mi], bfr[ni], acc[mi][ni], 0, 0, 0);
        }
    }

    // epilogue: C/D layout col = lane&15, row = quad*4 + reg (m89/m91-verified)
#pragma unroll
    for (int ni = 0; ni < 4; ni++) {
        const int col = blockN + wn + ni * 16 + l15;
        const float bv = bias[col];
        if (SCATTER) {   // qkv scatter (shown split): h = col/192, r = col%192
            const int h = col / 192;
            const int r = col - h * 192;
            u16* C = (u16*)Cv;
#pragma unroll
            for (int mi = 0; mi < 4; mi++)
#pragma unroll
                for (int reg = 0; reg < 4; reg++) {
                    const int row = blockM + wm + mi * 16 + quad * 4 + reg;
                    const int b = row >> 11, t = row & 2047;
                    C[((size_t)((b * HH + h) * TT + t)) * 192 + r] =
                        f2bf(acc[mi][ni][reg] + bv);
                }
        } else {         // fp32 dense output
            float* C = (float*)Cv;
#pragma unroll
            for (int mi = 0; mi < 4; mi++)
#pragma unroll
                for (int reg = 0; reg < 4; reg++) {
                    const int row = blockM + wm + mi * 16 + quad * 4 + reg;
                    C[(size_t)row * N + col] = acc[mi][ni][reg] + bv;
                }
        }
    }
}

// ---------------- Flash attention (max-free online softmax, bf16 qkv ws) ----------
// grid (T/128, B*H), 256 threads = 4 waves, each wave 32 Q-rows (2 m-tiles).
// Bc=64. att_v overwrites the q-slot (own rows only; k/v slots never written).
__global__ __launch_bounds__(256) void attn_fwd(u16* __restrict__ qkv) {
    __shared__ u16 Ks[64 * 64];        // 8 KB  K-tile  [s][d]   (swizzled)
    __shared__ u16 Vts[64 * 64];       // 8 KB  V-tile transposed [d][s] (swizzled)
    __shared__ u16 Ps[4 * 32 * 64];    // 16 KB P per wave [row][s] (swizzled)

    const int tid  = threadIdx.x;
    const int lane = tid & 63;
    const int wave = tid >> 6;
    const int quad = lane >> 4;
    const int l15  = lane & 15;

    const int bh = blockIdx.y;
    const int t0 = blockIdx.x * 128;
    u16* Qg = qkv + (size_t)bh * TT * 192;

    // Q fragments in registers (A-layout: m = lane&15, k = quad*8 + j)
    bf16x8 qf[2][2];
#pragma unroll
    for (int mi = 0; mi < 2; mi++) {
        const int trow = t0 + wave * 32 + mi * 16 + l15;
#pragma unroll
        for (int ks = 0; ks < 2; ks++)
            qf[mi][ks] = *(const bf16x8*)(Qg + (size_t)trow * 192 + ks * 32 + quad * 8);
    }

    floatx4 o[2][4];
#pragma unroll
    for (int mi = 0; mi < 2; mi++)
#pragma unroll
        for (int di = 0; di < 4; di++) o[mi][di] = (floatx4){0.f, 0.f, 0.f, 0.f};
    float l_run[2][4] = {{0.f, 0.f, 0.f, 0.f}, {0.f, 0.f, 0.f, 0.f}};

    const float cexp = 0.18033688f;    // log2(e)/8 : exp(s/8) = exp2(s*cexp)
    const int srow = lane >> 3;
    const int scol = (lane & 7) * 8;
    const int vs   = lane;             // V staging: s = lane
    const int vd0  = wave * 16;

    for (int s0 = 0; s0 < TT; s0 += 64) {
        // global loads into registers first (no LDS hazard)
        bf16x8 kt[2];
#pragma unroll
        for (int i = 0; i < 2; i++)
            kt[i] = *(const bf16x8*)(Qg + (size_t)(s0 + (i * 4 + wave) * 8 + srow) * 192
                                     + 64 + scol);
        const u16* vp = Qg + (size_t)(s0 + vs) * 192 + 128 + vd0;
        bf16x8 v0 = *(const bf16x8*)vp;
        bf16x8 v1 = *(const bf16x8*)(vp + 8);

        __syncthreads();   // previous iteration's Ks/Vts/Ps readers done
#pragma unroll
        for (int i = 0; i < 2; i++)
            *(bf16x8*)&Ks[sw8((i * 4 + wave) * 8 + srow, lane & 7)] = kt[i];
        {   // Vts scalar writes: row = vd0+j, u16 col = vs -> slot vs>>3, off vs&7
            const int vslot = vs >> 3, voff = vs & 7;
#pragma unroll
            for (int j = 0; j < 8; j++) {
                const int row = vd0 + j;
                Vts[row * 64 + (((vslot ^ (row & 7)) & 7) << 3) + voff] = (u16)v0[j];
            }
#pragma unroll
            for (int j = 0; j < 8; j++) {
                const int row = vd0 + 8 + j;
                Vts[row * 64 + (((vslot ^ (row & 7)) & 7) << 3) + voff] = (u16)v1[j];
            }
        }
        __syncthreads();

        // S = Q @ K^T  (2 m-tiles x 4 n-tiles)
        floatx4 s_acc[2][4];
#pragma unroll
        for (int mi = 0; mi < 2; mi++)
#pragma unroll
            for (int ni = 0; ni < 4; ni++) s_acc[mi][ni] = (floatx4){0.f, 0.f, 0.f, 0.f};
#pragma unroll
        for (int ks = 0; ks < 2; ks++) {
            const int slot = ks * 4 + quad;
            bf16x8 kf[4];
#pragma unroll
            for (int ni = 0; ni < 4; ni++)
                kf[ni] = *(const bf16x8*)&Ks[sw8(ni * 16 + l15, slot)];
#pragma unroll
            for (int mi = 0; mi < 2; mi++)
#pragma unroll
                for (int ni = 0; ni < 4; ni++)
                    s_acc[mi][ni] = __builtin_amdgcn_mfma_f32_16x16x32_bf16(
                        qf[mi][ks], kf[ni], s_acc[mi][ni], 0, 0, 0);
        }

        // P = exp2(S*cexp): C/D-layout -> Ps (per-wave region), row sums
#pragma unroll
        for (int mi = 0; mi < 2; mi++) {
            floatx4 rsum = (floatx4){0.f, 0.f, 0.f, 0.f};
#pragma unroll
            for (int ni = 0; ni < 4; ni++) {
                const int pslot = ni * 2 + (l15 >> 3);   // u16 col = ni*16+l15
                const int poff  = l15 & 7;
                floatx4 p;
#pragma unroll
                for (int reg = 0; reg < 4; reg++) {
                    p[reg] = exp2f(s_acc[mi][ni][reg] * cexp);
                    const int row = mi * 16 + quad * 4 + reg;
                    Ps[wave * 2048 + row * 64 + (((pslot ^ (row & 7)) & 7) << 3) + poff] =
                        f2bf(p[reg]);
                }
                rsum += p;
            }
#pragma unroll
            for (int reg = 0; reg < 4; reg++) {
                float v = rsum[reg];
                v += __shfl_xor(v, 1);
                v += __shfl_xor(v, 2);
                v += __shfl_xor(v, 4);
                v += __shfl_xor(v, 8);
                l_run[mi][reg] += v;   // row ownership (quad*4+reg) matches O layout
            }
        }

        __syncthreads();   // Ps writes visible before A-layout reads

        // O += P @ V   (A = Ps rows, B = Vts rows = d)
#pragma unroll
        for (int ks = 0; ks < 2; ks++) {
            const int slot = ks * 4 + quad;
            bf16x8 vf[4], pf[2];
#pragma unroll
            for (int di = 0; di < 4; di++)
                vf[di] = *(const bf16x8*)&Vts[sw8(di * 16 + l15, slot)];
#pragma unroll
            for (int mi = 0; mi < 2; mi++)
                pf[mi] = *(const bf16x8*)&Ps[wave * 2048 + sw8(mi * 16 + l15, slot)];
#pragma unroll
            for (int mi = 0; mi < 2; mi++)
#pragma unroll
                for (int di = 0; di < 4; di++)
                    o[mi][di] = __builtin_amdgcn_mfma_f32_16x16x32_bf16(
                        pf[mi], vf[di], o[mi][di], 0, 0, 0);
        }
    }

    // normalize, write att_v (bf16) into the q-slot — own rows only
#pragma unroll
    for (int mi = 0; mi < 2; mi++)
#pragma unroll
        for (int reg = 0; reg < 4; reg++) {
            const float inv_l = 1.0f / l_run[mi][reg];
            const int trow = t0 + wave * 32 + mi * 16 + quad * 4 + reg;
#pragma unroll
            for (int di = 0; di < 4; di++)
                Qg[(size_t)trow * 192 + di * 16 + l15] = f2bf(o[mi][di][reg] * inv_l);
        }
}

extern "C" void kernel_launch(void* const* d_in, const int* in_sizes, int n_in,
                              void* d_out, int out_size, void* d_ws, size_t ws_size,
                              hipStream_t stream) {
    (void)out_size; (void)ws_size;
    float* out = (float*)d_out;   // fp32 (R11-confirmed)

    // role assignment by unique element count (robust; dict order verified R6)
    const float *x = nullptr, *wq = nullptr, *bq = nullptr, *wo = nullptr, *bo = nullptr;
    int found = 0;
    for (int i = 0; i < n_in && i < 8; i++) {
        switch (in_sizes[i]) {
            case 8388608: x  = (const float*)d_in[i]; found |= 1;  break;
            case 3145728: wq = (const float*)d_in[i]; found |= 2;  break;
            case 3072:    bq = (const float*)d_in[i]; found |= 4;  break;
            case 1048576: wo = (const float*)d_in[i]; found |= 8;  break;
            case 1024:    bo = (const float*)d_in[i]; found |= 16; break;
        }
    }
    if (found != 31) {
        x  = (const float*)d_in[0]; wq = (const float*)d_in[1];
        bq = (const float*)d_in[2]; wo = (const float*)d_in[3];
        bo = (const float*)d_in[4];
    }

    u16* qkv = (u16*)d_ws;   // 48 MiB (ws >= 48MiB+64 verified R6-R10)

    // Stage 1: qkv = x @ W_qkv^T + b_qkv -> scatter [bh][t][192] bf16
    gemm_bt<1, 0><<<dim3(3 * CC / 128, BB * TT / 128), 256, 0, stream>>>(
        x, wq, bq, qkv, CC, 3 * CC);
    // Stage 2: flash attention, att_v -> q-slot in place
    attn_fwd<<<dim3(TT / 128, BB * HH), 256, 0, stream>>>(qkv);
    // Stage 3: out = att_v @ W_out^T + b_out (fp32 out)
    gemm_bt<0, 1><<<dim3(CC / 128, BB * TT / 128), 256, 0, stream>>>(
        qkv, wo, bo, out, CC, CC);
}

// Round 2
// 387.792 us; speedup vs baseline: 1.0978x; 1.0257x over previous
//
#include <hip/hip_runtime.h>
#include <hip/hip_bf16.h>

// ROUND 14: cut VALU overhead — HW bf16 cvt + raw v_exp + drop wave-private barrier.
// Contract (R11 PASS, absmax 4.9e-4): inputs fp32 dict-order, output fp32,
// shown interleaved split (head h owns qkv channels [h*192,(h+1)*192)),
// scale 1/8, out = att_v @ W_out^T + b_out. ws: qkv [b*16+h][t][192] bf16
// (48 MiB, in-place q-slot for att_v — audited R6-R11).
// R13: LDS XOR-swizzle -> SQ_LDS_BANK_CONFLICT 3.99e7 -> 0 (attn 235->214us).
// R14 changes (attn now VALU/LDS-instr bound: VALUBusy 52%, MfmaUtil 13.5%):
//  (a) f2bf: manual 4-op RNE pack -> __float2bfloat16 (v_cvt_pk_bf16_f32, RNE).
//  (b) exp2f (OCML wrapper) -> __builtin_amdgcn_exp2f (raw v_exp_f32).
//  (c) removed 3rd __syncthreads in attn: Ps is wave-private (wave*2048 region,
//      same-wave RAW ordered by lgkmcnt); top barrier still guards Ks/Vts.

typedef unsigned short u16;
typedef short bf16x8 __attribute__((ext_vector_type(8)));   // 8 bf16 = 4 VGPRs
typedef float floatx4 __attribute__((ext_vector_type(4)));

#define BB 4
#define TT 2048
#define CC 1024
#define HH 16

#if __has_builtin(__builtin_amdgcn_exp2f)
#define EXP2(x) __builtin_amdgcn_exp2f(x)
#else
#define EXP2(x) exp2f(x)
#endif

__device__ __forceinline__ float bf2f(u16 u) {
    union { unsigned v; float f; } x; x.v = ((unsigned)u) << 16; return x.f;
}
// HW RNE f32->bf16 (v_cvt_pk_bf16_f32 on gfx950; m240: casts beat hand asm)
__device__ __forceinline__ u16 f2bf(float f) {
    __hip_bfloat16 h = __float2bfloat16(f);
    u16 r; __builtin_memcpy(&r, &h, 2); return r;
}
// 8 contiguous fp32 -> bf16x8 (two 16B loads + HW RNE pack)
__device__ __forceinline__ bf16x8 cvt8(const float* p) {
    floatx4 a = *(const floatx4*)p;
    floatx4 b = *(const floatx4*)(p + 4);
    bf16x8 r;
    r[0] = (short)f2bf(a[0]); r[1] = (short)f2bf(a[1]);
    r[2] = (short)f2bf(a[2]); r[3] = (short)f2bf(a[3]);
    r[4] = (short)f2bf(b[0]); r[5] = (short)f2bf(b[1]);
    r[6] = (short)f2bf(b[2]); r[7] = (short)f2bf(b[3]);
    return r;
}
// XOR-swizzled u16 index into a [R][64] u16 tile for a 16B slot (slot=0..7).
__device__ __forceinline__ int sw8(int row, int slot) {
    return row * 64 + (((slot ^ (row & 7)) & 7) << 3);
}

// ---------------- GEMM: C = A @ B^T + bias ----------------------------------------
// 128x128 tile, BK=64, 256 threads = 4 waves (2x2), each wave 64x64 via 4x4 MFMA.
// SCATTER=1: C -> qkv ws scatter (bf16), shown split h=col/192.
// SCATTER=0: C -> fp32 out, A gathered from q-slots (QSLOT=1).
template <int SCATTER, int QSLOT>
__global__ __launch_bounds__(256) void gemm_bt(const void* __restrict__ Av,
                                               const float* __restrict__ Bw,
                                               const float* __restrict__ bias,
                                               void* __restrict__ Cv,
                                               int K, int N) {
    __shared__ u16 As[128 * 64];   // 16 KB
    __shared__ u16 Bs[128 * 64];   // 16 KB

    const int tid  = threadIdx.x;
    const int lane = tid & 63;
    const int wave = tid >> 6;
    const int quad = lane >> 4;
    const int l15  = lane & 15;
    const int wm   = (wave >> 1) * 64;
    const int wn   = (wave & 1) * 64;
    const int blockM = blockIdx.y * 128;
    const int blockN = blockIdx.x * 128;

    floatx4 acc[4][4];
#pragma unroll
    for (int i = 0; i < 4; i++)
#pragma unroll
        for (int j = 0; j < 4; j++) acc[i][j] = (floatx4){0.f, 0.f, 0.f, 0.f};

    const int srow = lane >> 3;        // 0..7: row within an 8-row chunk
    const int scol = (lane & 7) * 8;   // 0..56: col; srow*64+scol == lane*8

    for (int k0 = 0; k0 < K; k0 += 64) {
        bf16x8 at[4], bt[4];
#pragma unroll
        for (int i = 0; i < 4; i++) {
            const int row = blockM + (i * 4 + wave) * 8 + srow;
            if (QSLOT) {   // A = att_v in q-slots: k0 selects head (BK==hs==64)
                const int b = row >> 11, t = row & 2047, h = k0 >> 6;
                at[i] = *(const bf16x8*)((const u16*)Av
                         + ((size_t)((b * HH + h) * TT + t)) * 192 + scol);
            } else {       // A = x, fp32 -> bf16
                at[i] = cvt8((const float*)Av + (size_t)row * K + k0 + scol);
            }
        }
#pragma unroll
        for (int i = 0; i < 4; i++)
            bt[i] = cvt8(Bw + (size_t)(blockN + (i * 4 + wave) * 8 + srow) * K + k0 + scol);

        __syncthreads();   // prev iteration's LDS readers done
#pragma unroll
        for (int i = 0; i < 4; i++)
            *(bf16x8*)&As[sw8((i * 4 + wave) * 8 + srow, lane & 7)] = at[i];
#pragma unroll
        for (int i = 0; i < 4; i++)
            *(bf16x8*)&Bs[sw8((i * 4 + wave) * 8 + srow, lane & 7)] = bt[i];
        __syncthreads();

#pragma unroll
        for (int ks = 0; ks < 2; ks++) {
            const int slot = ks * 4 + quad;   // 16B slot index of ko
            bf16x8 af[4], bfr[4];
#pragma unroll
            for (int mi = 0; mi < 4; mi++)
                af[mi] = *(const bf16x8*)&As[sw8(wm + mi * 16 + l15, slot)];
#pragma unroll
            for (int ni = 0; ni < 4; ni++)
                bfr[ni] = *(const bf16x8*)&Bs[sw8(wn + ni * 16 + l15, slot)];
#pragma unroll
            for (int mi = 0; mi < 4; mi++)
#pragma unroll
                for (int ni = 0; ni < 4; ni++)
                    acc[mi][ni] = __builtin_amdgcn_mfma_f32_16x16x32_bf16(
                        af[mi], bfr[ni], acc[mi][ni], 0, 0, 0);
        }
    }

    // epilogue: C/D layout col = lane&15, row = quad*4 + reg (m89/m91-verified)
#pragma unroll
    for (int ni = 0; ni < 4; ni++) {
        const int col = blockN + wn + ni * 16 + l15;
        const float bv = bias[col];
        if (SCATTER) {   // qkv scatter (shown split): h = col/192, r = col%192
            const int h = col / 192;
            const int r = col - h * 192;
            u16* C = (u16*)Cv;
#pragma unroll
            for (int mi = 0; mi < 4; mi++)
#pragma unroll
                for (int reg = 0; reg < 4; reg++) {
                    const int row = blockM + wm + mi * 16 + quad * 4 + reg;
                    const int b = row >> 11, t = row & 2047;
                    C[((size_t)((b * HH + h) * TT + t)) * 192 + r] =
                        f2bf(acc[mi][ni][reg] + bv);
                }
        } else {         // fp32 dense output
            float* C = (float*)Cv;
#pragma unroll
            for (int mi = 0; mi < 4; mi++)
#pragma unroll
                for (int reg = 0; reg < 4; reg++) {
                    const int row = blockM + wm + mi * 16 + quad * 4 + reg;
                    C[(size_t)row * N + col] = acc[mi][ni][reg] + bv;
                }
        }
    }
}

// ---------------- Flash attention (max-free online softmax, bf16 qkv ws) ----------
// grid (T/128, B*H), 256 threads = 4 waves, each wave 32 Q-rows (2 m-tiles).
// Bc=64. att_v overwrites the q-slot (own rows only; k/v slots never written).
__global__ __launch_bounds__(256) void attn_fwd(u16* __restrict__ qkv) {
    __shared__ u16 Ks[64 * 64];        // 8 KB  K-tile  [s][d]   (swizzled)
    __shared__ u16 Vts[64 * 64];       // 8 KB  V-tile transposed [d][s] (swizzled)
    __shared__ u16 Ps[4 * 32 * 64];    // 16 KB P per wave [row][s] (swizzled)

    const int tid  = threadIdx.x;
    const int lane = tid & 63;
    const int wave = tid >> 6;
    const int quad = lane >> 4;
    const int l15  = lane & 15;

    const int bh = blockIdx.y;
    const int t0 = blockIdx.x * 128;
    u16* Qg = qkv + (size_t)bh * TT * 192;

    // Q fragments in registers (A-layout: m = lane&15, k = quad*8 + j)
    bf16x8 qf[2][2];
#pragma unroll
    for (int mi = 0; mi < 2; mi++) {
        const int trow = t0 + wave * 32 + mi * 16 + l15;
#pragma unroll
        for (int ks = 0; ks < 2; ks++)
            qf[mi][ks] = *(const bf16x8*)(Qg + (size_t)trow * 192 + ks * 32 + quad * 8);
    }

    floatx4 o[2][4];
#pragma unroll
    for (int mi = 0; mi < 2; mi++)
#pragma unroll
        for (int di = 0; di < 4; di++) o[mi][di] = (floatx4){0.f, 0.f, 0.f, 0.f};
    float l_run[2][4] = {{0.f, 0.f, 0.f, 0.f}, {0.f, 0.f, 0.f, 0.f}};

    const float cexp = 0.18033688f;    // log2(e)/8 : exp(s/8) = exp2(s*cexp)
    const int srow = lane >> 3;
    const int scol = (lane & 7) * 8;
    const int vs   = lane;             // V staging: s = lane
    const int vd0  = wave * 16;

    for (int s0 = 0; s0 < TT; s0 += 64) {
        // global loads into registers first (no LDS hazard)
        bf16x8 kt[2];
#pragma unroll
        for (int i = 0; i < 2; i++)
            kt[i] = *(const bf16x8*)(Qg + (size_t)(s0 + (i * 4 + wave) * 8 + srow) * 192
                                     + 64 + scol);
        const u16* vp = Qg + (size_t)(s0 + vs) * 192 + 128 + vd0;
        bf16x8 v0 = *(const bf16x8*)vp;
        bf16x8 v1 = *(const bf16x8*)(vp + 8);

        __syncthreads();   // previous iteration's Ks/Vts/Ps readers done
#pragma unroll
        for (int i = 0; i < 2; i++)
            *(bf16x8*)&Ks[sw8((i * 4 + wave) * 8 + srow, lane & 7)] = kt[i];
        {   // Vts scalar writes: row = vd0+j, u16 col = vs -> slot vs>>3, off vs&7
            const int vslot = vs >> 3, voff = vs & 7;
#pragma unroll
            for (int j = 0; j < 8; j++) {
                const int row = vd0 + j;
                Vts[row * 64 + (((vslot ^ (row & 7)) & 7) << 3) + voff] = (u16)v0[j];
            }
#pragma unroll
            for (int j = 0; j < 8; j++) {
                const int row = vd0 + 8 + j;
                Vts[row * 64 + (((vslot ^ (row & 7)) & 7) << 3) + voff] = (u16)v1[j];
            }
        }
        __syncthreads();

        // S = Q @ K^T  (2 m-tiles x 4 n-tiles)
        floatx4 s_acc[2][4];
#pragma unroll
        for (int mi = 0; mi < 2; mi++)
#pragma unroll
            for (int ni = 0; ni < 4; ni++) s_acc[mi][ni] = (floatx4){0.f, 0.f, 0.f, 0.f};
#pragma unroll
        for (int ks = 0; ks < 2; ks++) {
            const int slot = ks * 4 + quad;
            bf16x8 kf[4];
#pragma unroll
            for (int ni = 0; ni < 4; ni++)
                kf[ni] = *(const bf16x8*)&Ks[sw8(ni * 16 + l15, slot)];
#pragma unroll
            for (int mi = 0; mi < 2; mi++)
#pragma unroll
                for (int ni = 0; ni < 4; ni++)
                    s_acc[mi][ni] = __builtin_amdgcn_mfma_f32_16x16x32_bf16(
                        qf[mi][ks], kf[ni], s_acc[mi][ni], 0, 0, 0);
        }

        // P = exp2(S*cexp): C/D-layout -> Ps (per-wave region), row sums
#pragma unroll
        for (int mi = 0; mi < 2; mi++) {
            floatx4 rsum = (floatx4){0.f, 0.f, 0.f, 0.f};
#pragma unroll
            for (int ni = 0; ni < 4; ni++) {
                const int pslot = ni * 2 + (l15 >> 3);   // u16 col = ni*16+l15
                const int poff  = l15 & 7;
                floatx4 p;
#pragma unroll
                for (int reg = 0; reg < 4; reg++) {
                    p[reg] = EXP2(s_acc[mi][ni][reg] * cexp);
                    const int row = mi * 16 + quad * 4 + reg;
                    Ps[wave * 2048 + row * 64 + (((pslot ^ (row & 7)) & 7) << 3) + poff] =
                        f2bf(p[reg]);
                }
                rsum += p;
            }
#pragma unroll
            for (int reg = 0; reg < 4; reg++) {
                float v = rsum[reg];
                v += __shfl_xor(v, 1);
                v += __shfl_xor(v, 2);
                v += __shfl_xor(v, 4);
                v += __shfl_xor(v, 8);
                l_run[mi][reg] += v;   // row ownership (quad*4+reg) matches O layout
            }
        }

        // NO barrier here: Ps region is wave-private; same-wave LDS RAW is
        // ordered by compiler-inserted lgkmcnt waits.

        // O += P @ V   (A = Ps rows, B = Vts rows = d)
#pragma unroll
        for (int ks = 0; ks < 2; ks++) {
            const int slot = ks * 4 + quad;
            bf16x8 vf[4], pf[2];
#pragma unroll
            for (int di = 0; di < 4; di++)
                vf[di] = *(const bf16x8*)&Vts[sw8(di * 16 + l15, slot)];
#pragma unroll
            for (int mi = 0; mi < 2; mi++)
                pf[mi] = *(const bf16x8*)&Ps[wave * 2048 + sw8(mi * 16 + l15, slot)];
#pragma unroll
            for (int mi = 0; mi < 2; mi++)
#pragma unroll
                for (int di = 0; di < 4; di++)
                    o[mi][di] = __builtin_amdgcn_mfma_f32_16x16x32_bf16(
                        pf[mi], vf[di], o[mi][di], 0, 0, 0);
        }
    }

    // normalize, write att_v (bf16) into the q-slot — own rows only
#pragma unroll
    for (int mi = 0; mi < 2; mi++)
#pragma unroll
        for (int reg = 0; reg < 4; reg++) {
            const float inv_l = 1.0f / l_run[mi][reg];
            const int trow = t0 + wave * 32 + mi * 16 + quad * 4 + reg;
#pragma unroll
            for (int di = 0; di < 4; di++)
                Qg[(size_t)trow * 192 + di * 16 + l15] = f2bf(o[mi][di][reg] * inv_l);
        }
}

extern "C" void kernel_launch(void* const* d_in, const int* in_sizes, int n_in,
                              void* d_out, int out_size, void* d_ws, size_t ws_size,
                              hipStream_t stream) {
    (void)out_size; (void)ws_size;
    float* out = (float*)d_out;   // fp32 (R11-confirmed)

    // role assignment by unique element count (robust; dict order verified R6)
    const float *x = nullptr, *wq = nullptr, *bq = nullptr, *wo = nullptr, *bo = nullptr;
    int found = 0;
    for (int i = 0; i < n_in && i < 8; i++) {
        switch (in_sizes[i]) {
            case 8388608: x  = (const float*)d_in[i]; found |= 1;  break;
            case 3145728: wq = (const float*)d_in[i]; found |= 2;  break;
            case 3072:    bq = (const float*)d_in[i]; found |= 4;  break;
            case 1048576: wo = (const float*)d_in[i]; found |= 8;  break;
            case 1024:    bo = (const float*)d_in[i]; found |= 16; break;
        }
    }
    if (found != 31) {
        x  = (const float*)d_in[0]; wq = (const float*)d_in[1];
        bq = (const float*)d_in[2]; wo = (const float*)d_in[3];
        bo = (const float*)d_in[4];
    }

    u16* qkv = (u16*)d_ws;   // 48 MiB (ws >= 48MiB+64 verified R6-R10)

    // Stage 1: qkv = x @ W_qkv^T + b_qkv -> scatter [bh][t][192] bf16
    gemm_bt<1, 0><<<dim3(3 * CC / 128, BB * TT / 128), 256, 0, stream>>>(
        x, wq, bq, qkv, CC, 3 * CC);
    // Stage 2: flash attention, att_v -> q-slot in place
    attn_fwd<<<dim3(TT / 128, BB * HH), 256, 0, stream>>>(qkv);
    // Stage 3: out = att_v @ W_out^T + b_out (fp32 out)
    gemm_bt<0, 1><<<dim3(CC / 128, BB * TT / 128), 256, 0, stream>>>(
        qkv, wo, bo, out, CC, CC);
}

// Round 3
// 334.890 us; speedup vs baseline: 1.2712x; 1.1580x over previous
//
#include <hip/hip_runtime.h>
#include <hip/hip_bf16.h>

// ROUND 15: T12 swapped-QK^T — P stays in registers, Ps LDS round-trip deleted.
// Contract (R11 PASS, absmax 4.9e-4): inputs fp32 dict-order, output fp32,
// shown interleaved split (head h owns qkv channels [h*192,(h+1)*192)),
// scale 1/8, out = att_v @ W_out^T + b_out. ws: qkv [b*16+h][t][192] bf16.
// R13: LDS XOR-swizzle -> bank conflicts 3.99e7 -> 0 (attn 235->214us).
// R14: HW bf16 cvt + raw v_exp + barrier drop (attn 214->190us, VALU 52->35%).
// R15: attn was DS-instruction bound (70 DS ops/iter: 32 scalar Ps writes +
// 4 pf reads + 32 shfl-bpermutes vs 160cy MFMA). Swapped S^T = mfma(K,Q) puts
// P[q=l15][s] lane-local; redistribution C/D->A-fragment done in-register via
// permlane32_swap + permlane16_swap per (qi,ks,h) — derivation checked
// index-by-index vs m89 layout. DS ops/iter 70 -> 38; Ps (16KB) freed.

typedef unsigned short u16;
typedef short bf16x8 __attribute__((ext_vector_type(8)));   // 8 bf16 = 4 VGPRs
typedef float floatx4 __attribute__((ext_vector_type(4)));

#define BB 4
#define TT 2048
#define CC 1024
#define HH 16

#if __has_builtin(__builtin_amdgcn_exp2f)
#define EXP2(x) __builtin_amdgcn_exp2f(x)
#else
#define EXP2(x) exp2f(x)
#endif

__device__ __forceinline__ u16 f2bf(float f) {
    __hip_bfloat16 h = __float2bfloat16(f);
    u16 r; __builtin_memcpy(&r, &h, 2); return r;
}
// pack 2 f32 -> u32 of 2 bf16 (lo in low half), RNE
__device__ __forceinline__ unsigned pkbf(float lo, float hi) {
    __hip_bfloat162 h2 = __float22bfloat162_rn(float2{lo, hi});
    unsigned r; __builtin_memcpy(&r, &h2, 4); return r;
}
// 8 contiguous fp32 -> bf16x8 (two 16B loads + HW RNE pack)
__device__ __forceinline__ bf16x8 cvt8(const float* p) {
    floatx4 a = *(const floatx4*)p;
    floatx4 b = *(const floatx4*)(p + 4);
    bf16x8 r;
    r[0] = (short)f2bf(a[0]); r[1] = (short)f2bf(a[1]);
    r[2] = (short)f2bf(a[2]); r[3] = (short)f2bf(a[3]);
    r[4] = (short)f2bf(b[0]); r[5] = (short)f2bf(b[1]);
    r[6] = (short)f2bf(b[2]); r[7] = (short)f2bf(b[3]);
    return r;
}
// XOR-swizzled u16 index into a [R][64] u16 tile for a 16B slot (slot=0..7).
__device__ __forceinline__ int sw8(int row, int slot) {
    return row * 64 + (((slot ^ (row & 7)) & 7) << 3);
}

// ---- cross-lane half swaps: a' = [a.lo, b.lo-ish] per gfx950 permlane*_swap ----
// pl32: a'[l] = l<32 ? a[l] : b[l-32];  b'[l] = l<32 ? a[l+32] : b[l]
__device__ __forceinline__ void pl32swap(unsigned& a, unsigned& b) {
#if __has_builtin(__builtin_amdgcn_permlane32_swap)
    typedef unsigned u32x2 __attribute__((ext_vector_type(2)));
    u32x2 r = __builtin_amdgcn_permlane32_swap(a, b, false, false);
    a = r[0]; b = r[1];
#else
    const bool up = (threadIdx.x & 32) != 0;
    unsigned as = (unsigned)__shfl_xor((int)a, 32);
    unsigned bs = (unsigned)__shfl_xor((int)b, 32);
    unsigned na = up ? bs : a;
    unsigned nb = up ? b : as;
    a = na; b = nb;
#endif
}
// pl16: a'[l] = (l&16) ? b[l-16] : a[l];  b'[l] = (l&16) ? b[l] : a[l+16]
__device__ __forceinline__ void pl16swap(unsigned& a, unsigned& b) {
#if __has_builtin(__builtin_amdgcn_permlane16_swap)
    typedef unsigned u32x2 __attribute__((ext_vector_type(2)));
    u32x2 r = __builtin_amdgcn_permlane16_swap(a, b, false, false);
    a = r[0]; b = r[1];
#else
    const bool up = (threadIdx.x & 16) != 0;
    unsigned as = (unsigned)__shfl_xor((int)a, 16);
    unsigned bs = (unsigned)__shfl_xor((int)b, 16);
    unsigned na = up ? bs : a;
    unsigned nb = up ? b : as;
    a = na; b = nb;
#endif
}

// ---------------- GEMM: C = A @ B^T + bias (unchanged from R14) -------------------
template <int SCATTER, int QSLOT>
__global__ __launch_bounds__(256) void gemm_bt(const void* __restrict__ Av,
                                               const float* __restrict__ Bw,
                                               const float* __restrict__ bias,
                                               void* __restrict__ Cv,
                                               int K, int N) {
    __shared__ u16 As[128 * 64];   // 16 KB
    __shared__ u16 Bs[128 * 64];   // 16 KB

    const int tid  = threadIdx.x;
    const int lane = tid & 63;
    const int wave = tid >> 6;
    const int quad = lane >> 4;
    const int l15  = lane & 15;
    const int wm   = (wave >> 1) * 64;
    const int wn   = (wave & 1) * 64;
    const int blockM = blockIdx.y * 128;
    const int blockN = blockIdx.x * 128;

    floatx4 acc[4][4];
#pragma unroll
    for (int i = 0; i < 4; i++)
#pragma unroll
        for (int j = 0; j < 4; j++) acc[i][j] = (floatx4){0.f, 0.f, 0.f, 0.f};

    const int srow = lane >> 3;        // 0..7: row within an 8-row chunk
    const int scol = (lane & 7) * 8;   // 0..56: col; srow*64+scol == lane*8

    for (int k0 = 0; k0 < K; k0 += 64) {
        bf16x8 at[4], bt[4];
#pragma unroll
        for (int i = 0; i < 4; i++) {
            const int row = blockM + (i * 4 + wave) * 8 + srow;
            if (QSLOT) {   // A = att_v in q-slots: k0 selects head (BK==hs==64)
                const int b = row >> 11, t = row & 2047, h = k0 >> 6;
                at[i] = *(const bf16x8*)((const u16*)Av
                         + ((size_t)((b * HH + h) * TT + t)) * 192 + scol);
            } else {       // A = x, fp32 -> bf16
                at[i] = cvt8((const float*)Av + (size_t)row * K + k0 + scol);
            }
        }
#pragma unroll
        for (int i = 0; i < 4; i++)
            bt[i] = cvt8(Bw + (size_t)(blockN + (i * 4 + wave) * 8 + srow) * K + k0 + scol);

        __syncthreads();   // prev iteration's LDS readers done
#pragma unroll
        for (int i = 0; i < 4; i++)
            *(bf16x8*)&As[sw8((i * 4 + wave) * 8 + srow, lane & 7)] = at[i];
#pragma unroll
        for (int i = 0; i < 4; i++)
            *(bf16x8*)&Bs[sw8((i * 4 + wave) * 8 + srow, lane & 7)] = bt[i];
        __syncthreads();

#pragma unroll
        for (int ks = 0; ks < 2; ks++) {
            const int slot = ks * 4 + quad;   // 16B slot index of ko
            bf16x8 af[4], bfr[4];
#pragma unroll
            for (int mi = 0; mi < 4; mi++)
                af[mi] = *(const bf16x8*)&As[sw8(wm + mi * 16 + l15, slot)];
#pragma unroll
            for (int ni = 0; ni < 4; ni++)
                bfr[ni] = *(const bf16x8*)&Bs[sw8(wn + ni * 16 + l15, slot)];
#pragma unroll
            for (int mi = 0; mi < 4; mi++)
#pragma unroll
                for (int ni = 0; ni < 4; ni++)
                    acc[mi][ni] = __builtin_amdgcn_mfma_f32_16x16x32_bf16(
                        af[mi], bfr[ni], acc[mi][ni], 0, 0, 0);
        }
    }

    // epilogue: C/D layout col = lane&15, row = quad*4 + reg (m89/m91-verified)
#pragma unroll
    for (int ni = 0; ni < 4; ni++) {
        const int col = blockN + wn + ni * 16 + l15;
        const float bv = bias[col];
        if (SCATTER) {   // qkv scatter (shown split): h = col/192, r = col%192
            const int h = col / 192;
            const int r = col - h * 192;
            u16* C = (u16*)Cv;
#pragma unroll
            for (int mi = 0; mi < 4; mi++)
#pragma unroll
                for (int reg = 0; reg < 4; reg++) {
                    const int row = blockM + wm + mi * 16 + quad * 4 + reg;
                    const int b = row >> 11, t = row & 2047;
                    C[((size_t)((b * HH + h) * TT + t)) * 192 + r] =
                        f2bf(acc[mi][ni][reg] + bv);
                }
        } else {         // fp32 dense output
            float* C = (float*)Cv;
#pragma unroll
            for (int mi = 0; mi < 4; mi++)
#pragma unroll
                for (int reg = 0; reg < 4; reg++) {
                    const int row = blockM + wm + mi * 16 + quad * 4 + reg;
                    C[(size_t)row * N + col] = acc[mi][ni][reg] + bv;
                }
        }
    }
}

// ---------------- Flash attention (swapped QK^T, in-register P) -------------------
// grid (T/128, B*H), 256 threads = 4 waves, each wave 32 Q-rows.
// S^T = mfma(K,Q): lane holds P[q=qi*16+l15][s=si*16+quad*4+reg].
// Redistribution to PV A-fragments via permlane32_swap+permlane16_swap.
__global__ __launch_bounds__(256) void attn_fwd(u16* __restrict__ qkv) {
    __shared__ u16 Ks[64 * 64];        // 8 KB  K-tile  [s][d]   (swizzled)
    __shared__ u16 Vts[64 * 64];       // 8 KB  V-tile transposed [d][s] (swizzled)

    const int tid  = threadIdx.x;
    const int lane = tid & 63;
    const int wave = tid >> 6;
    const int quad = lane >> 4;
    const int l15  = lane & 15;

    const int bh = blockIdx.y;
    const int t0 = blockIdx.x * 128;
    u16* Qg = qkv + (size_t)bh * TT * 192;

    // Q fragments (B-operand: n = q = l15, k = d = ks*32 + quad*8 + j)
    bf16x8 qf[2][2];
#pragma unroll
    for (int qi = 0; qi < 2; qi++) {
        const int trow = t0 + wave * 32 + qi * 16 + l15;
#pragma unroll
        for (int ks = 0; ks < 2; ks++)
            qf[qi][ks] = *(const bf16x8*)(Qg + (size_t)trow * 192 + ks * 32 + quad * 8);
    }

    floatx4 o[2][4];
#pragma unroll
    for (int qi = 0; qi < 2; qi++)
#pragma unroll
        for (int di = 0; di < 4; di++) o[qi][di] = (floatx4){0.f, 0.f, 0.f, 0.f};
    float l_run[2] = {0.f, 0.f};       // rowsum for q = qi*16 + l15

    const float cexp = 0.18033688f;    // log2(e)/8 : exp(s/8) = exp2(s*cexp)
    const int srow = lane >> 3;
    const int scol = (lane & 7) * 8;
    const int vs   = lane;             // V staging: s = lane
    const int vd0  = wave * 16;

    for (int s0 = 0; s0 < TT; s0 += 64) {
        // global loads into registers first (no LDS hazard)
        bf16x8 kt[2];
#pragma unroll
        for (int i = 0; i < 2; i++)
            kt[i] = *(const bf16x8*)(Qg + (size_t)(s0 + (i * 4 + wave) * 8 + srow) * 192
                                     + 64 + scol);
        const u16* vp = Qg + (size_t)(s0 + vs) * 192 + 128 + vd0;
        bf16x8 v0 = *(const bf16x8*)vp;
        bf16x8 v1 = *(const bf16x8*)(vp + 8);

        __syncthreads();   // previous iteration's Ks/Vts readers done
#pragma unroll
        for (int i = 0; i < 2; i++)
            *(bf16x8*)&Ks[sw8((i * 4 + wave) * 8 + srow, lane & 7)] = kt[i];
        {   // Vts scalar writes: row = d, u16 col = s -> slot vs>>3, off vs&7
            const int vslot = vs >> 3, voff = vs & 7;
#pragma unroll
            for (int j = 0; j < 8; j++) {
                const int row = vd0 + j;
                Vts[row * 64 + (((vslot ^ (row & 7)) & 7) << 3) + voff] = (u16)v0[j];
            }
#pragma unroll
            for (int j = 0; j < 8; j++) {
                const int row = vd0 + 8 + j;
                Vts[row * 64 + (((vslot ^ (row & 7)) & 7) << 3) + voff] = (u16)v1[j];
            }
        }
        __syncthreads();

        // S^T = K @ Q^T : s_acc[si][qi], lane = P[s=si*16+quad*4+reg][q=qi*16+l15]
        floatx4 s_acc[4][2];
#pragma unroll
        for (int si = 0; si < 4; si++)
#pragma unroll
            for (int qi = 0; qi < 2; qi++) s_acc[si][qi] = (floatx4){0.f, 0.f, 0.f, 0.f};
#pragma unroll
        for (int ks = 0; ks < 2; ks++) {
            const int slot = ks * 4 + quad;
            bf16x8 kf[4];
#pragma unroll
            for (int si = 0; si < 4; si++)
                kf[si] = *(const bf16x8*)&Ks[sw8(si * 16 + l15, slot)];
#pragma unroll
            for (int si = 0; si < 4; si++)
#pragma unroll
                for (int qi = 0; qi < 2; qi++)
                    s_acc[si][qi] = __builtin_amdgcn_mfma_f32_16x16x32_bf16(
                        kf[si], qf[qi][ks], s_acc[si][qi], 0, 0, 0);
        }

        // P = exp2(S*cexp) in-register; pack bf16 pairs; lane-local row sums
        unsigned c[4][2][2];
        floatx4 rs[2] = {(floatx4){0.f,0.f,0.f,0.f}, (floatx4){0.f,0.f,0.f,0.f}};
#pragma unroll
        for (int si = 0; si < 4; si++)
#pragma unroll
            for (int qi = 0; qi < 2; qi++) {
                floatx4 p;
#pragma unroll
                for (int r = 0; r < 4; r++) p[r] = EXP2(s_acc[si][qi][r] * cexp);
                rs[qi] += p;
                c[si][qi][0] = pkbf(p[0], p[1]);
                c[si][qi][1] = pkbf(p[2], p[3]);
            }
#pragma unroll
        for (int qi = 0; qi < 2; qi++) {
            float v = rs[qi][0] + rs[qi][1] + rs[qi][2] + rs[qi][3];
            v += __shfl_xor(v, 16);
            v += __shfl_xor(v, 32);
            l_run[qi] += v;            // full sum for q = qi*16 + l15
        }

        // redistribute C/D-layout P -> A-fragments pf[qi][ks]
        // word w of pf = c[2ks+(quad>>1)][qi][w&1] from source quad (quad&1)*2+(w>>1)
        // achieved by pl32swap then pl16swap (derived vs m89 layout):
        union PF { bf16x8 v; unsigned u[4]; } pf[2][2];
#pragma unroll
        for (int qi = 0; qi < 2; qi++)
#pragma unroll
            for (int ks = 0; ks < 2; ks++)
#pragma unroll
                for (int h = 0; h < 2; h++) {
                    unsigned a = c[2 * ks][qi][h];
                    unsigned b = c[2 * ks + 1][qi][h];
                    pl32swap(a, b);
                    pl16swap(a, b);
                    pf[qi][ks].u[h]     = a;   // w0 (h=0) / w1 (h=1)
                    pf[qi][ks].u[2 + h] = b;   // w2 (h=0) / w3 (h=1)
                }

        // O += P @ V   (A = pf regs, B = Vts rows = d)
#pragma unroll
        for (int ks = 0; ks < 2; ks++) {
            const int slot = ks * 4 + quad;
            bf16x8 vf[4];
#pragma unroll
            for (int di = 0; di < 4; di++)
                vf[di] = *(const bf16x8*)&Vts[sw8(di * 16 + l15, slot)];
#pragma unroll
            for (int qi = 0; qi < 2; qi++)
#pragma unroll
                for (int di = 0; di < 4; di++)
                    o[qi][di] = __builtin_amdgcn_mfma_f32_16x16x32_bf16(
                        pf[qi][ks].v, vf[di], o[qi][di], 0, 0, 0);
        }
    }

    // normalize, write att_v (bf16) into the q-slot — own rows only.
    // l_run is indexed by l15; O rows are quad*4+reg -> one-time shuffle.
#pragma unroll
    for (int qi = 0; qi < 2; qi++)
#pragma unroll
        for (int reg = 0; reg < 4; reg++) {
            const float lv = __shfl(l_run[qi], quad * 4 + reg);
            const float inv_l = 1.0f / lv;
            const int trow = t0 + wave * 32 + qi * 16 + quad * 4 + reg;
#pragma unroll
            for (int di = 0; di < 4; di++)
                Qg[(size_t)trow * 192 + di * 16 + l15] = f2bf(o[qi][di][reg] * inv_l);
        }
}

extern "C" void kernel_launch(void* const* d_in, const int* in_sizes, int n_in,
                              void* d_out, int out_size, void* d_ws, size_t ws_size,
                              hipStream_t stream) {
    (void)out_size; (void)ws_size;
    float* out = (float*)d_out;   // fp32 (R11-confirmed)

    // role assignment by unique element count (robust; dict order verified R6)
    const float *x = nullptr, *wq = nullptr, *bq = nullptr, *wo = nullptr, *bo = nullptr;
    int found = 0;
    for (int i = 0; i < n_in && i < 8; i++) {
        switch (in_sizes[i]) {
            case 8388608: x  = (const float*)d_in[i]; found |= 1;  break;
            case 3145728: wq = (const float*)d_in[i]; found |= 2;  break;
            case 3072:    bq = (const float*)d_in[i]; found |= 4;  break;
            case 1048576: wo = (const float*)d_in[i]; found |= 8;  break;
            case 1024:    bo = (const float*)d_in[i]; found |= 16; break;
        }
    }
    if (found != 31) {
        x  = (const float*)d_in[0]; wq = (const float*)d_in[1];
        bq = (const float*)d_in[2]; wo = (const float*)d_in[3];
        bo = (const float*)d_in[4];
    }

    u16* qkv = (u16*)d_ws;   // 48 MiB (ws >= 48MiB+64 verified R6-R10)

    // Stage 1: qkv = x @ W_qkv^T + b_qkv -> scatter [bh][t][192] bf16
    gemm_bt<1, 0><<<dim3(3 * CC / 128, BB * TT / 128), 256, 0, stream>>>(
        x, wq, bq, qkv, CC, 3 * CC);
    // Stage 2: flash attention, att_v -> q-slot in place
    attn_fwd<<<dim3(TT / 128, BB * HH), 256, 0, stream>>>(qkv);
    // Stage 3: out = att_v @ W_out^T + b_out (fp32 out)
    gemm_bt<0, 1><<<dim3(CC / 128, BB * TT / 128), 256, 0, stream>>>(
        qkv, wo, bo, out, CC, CC);
}

// Round 4
// 304.617 us; speedup vs baseline: 1.3975x; 1.0994x over previous
//
#include <hip/hip_runtime.h>
#include <hip/hip_bf16.h>

// ROUND 16: GEMM staging via global_load_lds (m97-step) + bf16 pre-pass.
// Contract (R11 PASS, absmax 4.9e-4): inputs fp32 dict-order, output fp32,
// shown interleaved split (head h owns qkv channels [h*192,(h+1)*192)),
// scale 1/8, out = att_v @ W_out^T + b_out. ws: qkv [b*16+h][t][192] bf16.
// R13: LDS XOR-swizzle -> bank conflicts 3.99e7 -> 0 (attn 235->214us).
// R14: HW bf16 cvt + raw v_exp + barrier drop (attn 214->190us).
// R15: swapped-QK^T in-register P (attn 190->136us, total 335us).
// R16: GEMMs were 199us = 345 TF, bound by fp32->bf16 cvt + register staging
// VALU (Common-mistake #1). New path: (a) prepass converts x/W_qkv/W_out to
// bf16 in ws (+24MB, ~12us); (b) gemm_lds stages via 8x global_load_lds
// width-16 per wave per K-step, LDS dest linear + inverse-swizzled global
// source column (G21 both-sides rule) so sw8 ds_reads stay conflict-free.
// Gated on ws_size >= 72MiB; falls back to R15 gemm_bt otherwise.

typedef unsigned short u16;
typedef short bf16x8 __attribute__((ext_vector_type(8)));   // 8 bf16 = 4 VGPRs
typedef float floatx4 __attribute__((ext_vector_type(4)));

#define BB 4
#define TT 2048
#define CC 1024
#define HH 16

#if __has_builtin(__builtin_amdgcn_exp2f)
#define EXP2(x) __builtin_amdgcn_exp2f(x)
#else
#define EXP2(x) exp2f(x)
#endif

__device__ __forceinline__ u16 f2bf(float f) {
    __hip_bfloat16 h = __float2bfloat16(f);
    u16 r; __builtin_memcpy(&r, &h, 2); return r;
}
// pack 2 f32 -> u32 of 2 bf16 (lo in low half), RNE
__device__ __forceinline__ unsigned pkbf(float lo, float hi) {
    __hip_bfloat162 h2 = __float22bfloat162_rn(float2{lo, hi});
    unsigned r; __builtin_memcpy(&r, &h2, 4); return r;
}
// 8 contiguous fp32 -> bf16x8 (two 16B loads + HW RNE pack)
__device__ __forceinline__ bf16x8 cvt8(const float* p) {
    floatx4 a = *(const floatx4*)p;
    floatx4 b = *(const floatx4*)(p + 4);
    bf16x8 r;
    r[0] = (short)f2bf(a[0]); r[1] = (short)f2bf(a[1]);
    r[2] = (short)f2bf(a[2]); r[3] = (short)f2bf(a[3]);
    r[4] = (short)f2bf(b[0]); r[5] = (short)f2bf(b[1]);
    r[6] = (short)f2bf(b[2]); r[7] = (short)f2bf(b[3]);
    return r;
}
// XOR-swizzled u16 index into a [R][64] u16 tile for a 16B slot (slot=0..7).
__device__ __forceinline__ int sw8(int row, int slot) {
    return row * 64 + (((slot ^ (row & 7)) & 7) << 3);
}
// async global->LDS, 16B/lane: dest = lds + lane*16 (wave-uniform base),
// src per-lane. Drained by the implicit vmcnt(0) before __syncthreads.
__device__ __forceinline__ void gll16(const u16* g, u16* l) {
    __builtin_amdgcn_global_load_lds(
        (const __attribute__((address_space(1))) unsigned*)g,
        (__attribute__((address_space(3))) unsigned*)l, 16, 0, 0);
}

// ---- cross-lane half swaps (gfx950 permlane*_swap, shfl fallback) ----
__device__ __forceinline__ void pl32swap(unsigned& a, unsigned& b) {
#if __has_builtin(__builtin_amdgcn_permlane32_swap)
    typedef unsigned u32x2 __attribute__((ext_vector_type(2)));
    u32x2 r = __builtin_amdgcn_permlane32_swap(a, b, false, false);
    a = r[0]; b = r[1];
#else
    const bool up = (threadIdx.x & 32) != 0;
    unsigned as = (unsigned)__shfl_xor((int)a, 32);
    unsigned bs = (unsigned)__shfl_xor((int)b, 32);
    unsigned na = up ? bs : a;
    unsigned nb = up ? b : as;
    a = na; b = nb;
#endif
}
__device__ __forceinline__ void pl16swap(unsigned& a, unsigned& b) {
#if __has_builtin(__builtin_amdgcn_permlane16_swap)
    typedef unsigned u32x2 __attribute__((ext_vector_type(2)));
    u32x2 r = __builtin_amdgcn_permlane16_swap(a, b, false, false);
    a = r[0]; b = r[1];
#else
    const bool up = (threadIdx.x & 16) != 0;
    unsigned as = (unsigned)__shfl_xor((int)a, 16);
    unsigned bs = (unsigned)__shfl_xor((int)b, 16);
    unsigned na = up ? bs : a;
    unsigned nb = up ? b : as;
    a = na; b = nb;
#endif
}

// ---------------- prepass: fp32 -> bf16 (x, W_qkv, W_out) -------------------------
__global__ __launch_bounds__(256) void cvt_all(const float* __restrict__ x,
                                               const float* __restrict__ wq,
                                               const float* __restrict__ wo,
                                               u16* __restrict__ xb,
                                               u16* __restrict__ wqb,
                                               u16* __restrict__ wob) {
    const int nx8 = 8388608 / 8, nq8 = 3145728 / 8, no8 = 1048576 / 8;
    const int n8 = nx8 + nq8 + no8;
    for (int i = blockIdx.x * blockDim.x + threadIdx.x; i < n8;
         i += gridDim.x * blockDim.x) {
        const float* src;
        u16* dst;
        if (i < nx8)            { src = x  + (size_t)i * 8;          dst = xb  + (size_t)i * 8; }
        else if (i < nx8 + nq8) { size_t j = i - nx8; src = wq + j * 8; dst = wqb + j * 8; }
        else                    { size_t j = i - nx8 - nq8; src = wo + j * 8; dst = wob + j * 8; }
        floatx4 a = *(const floatx4*)src;
        floatx4 b = *(const floatx4*)(src + 4);
        union { bf16x8 v; unsigned u[4]; } r;
        r.u[0] = pkbf(a[0], a[1]); r.u[1] = pkbf(a[2], a[3]);
        r.u[2] = pkbf(b[0], b[1]); r.u[3] = pkbf(b[2], b[3]);
        *(bf16x8*)dst = r.v;
    }
}

// ---------------- GEMM (bf16 inputs, global_load_lds staging) ---------------------
// 128x128 tile, BK=64, 256 threads = 4 waves (2x2), each wave 64x64 via 4x4 MFMA.
// Staging: wave w issues gll16 for A-chunks/B-chunks 4w..4w+3 (8-row chunks).
// LDS linear dest; lane fetches logical slot (l&7)^((l>>3)&7) -> content lands
// exactly at sw8 positions (involution audited R16).
template <int SCATTER, int QSLOT>
__global__ __launch_bounds__(256) void gemm_lds(const u16* __restrict__ Ab,
                                                const u16* __restrict__ Bb,
                                                const float* __restrict__ bias,
                                                void* __restrict__ Cv,
                                                int K, int N) {
    __shared__ u16 As[128 * 64];   // 16 KB
    __shared__ u16 Bs[128 * 64];   // 16 KB

    const int tid  = threadIdx.x;
    const int lane = tid & 63;
    const int wave = tid >> 6;
    const int quad = lane >> 4;
    const int l15  = lane & 15;
    const int wm   = (wave >> 1) * 64;
    const int wn   = (wave & 1) * 64;
    const int blockM = blockIdx.y * 128;
    const int blockN = blockIdx.x * 128;

    floatx4 acc[4][4];
#pragma unroll
    for (int i = 0; i < 4; i++)
#pragma unroll
        for (int j = 0; j < 4; j++) acc[i][j] = (floatx4){0.f, 0.f, 0.f, 0.f};

    const int lr = lane >> 3;                       // row within 8-row chunk
    const int scol = ((lane & 7) ^ (lr & 7)) * 8;   // inverse-swizzled source col

    for (int k0 = 0; k0 < K; k0 += 64) {
        __syncthreads();   // prev iteration's LDS readers done
#pragma unroll
        for (int i = 0; i < 4; i++) {
            const int c = wave * 4 + i;             // chunk 0..15
            const int row = blockM + c * 8 + lr;
            const u16* src;
            if (QSLOT) {   // A = att_v in q-slots: k0 selects head (BK==hs==64)
                const int b = row >> 11, t = row & 2047, h = k0 >> 6;
                src = Ab + ((size_t)((b * HH + h) * TT + t)) * 192 + scol;
            } else {
                src = Ab + (size_t)row * K + k0 + scol;
            }
            gll16(src, &As[c * 512]);
        }
#pragma unroll
        for (int i = 0; i < 4; i++) {
            const int c = wave * 4 + i;
            const int row = blockN + c * 8 + lr;
            gll16(Bb + (size_t)row * K + k0 + scol, &Bs[c * 512]);
        }
        __syncthreads();   // implicit vmcnt(0) drain before barrier

#pragma unroll
        for (int ks = 0; ks < 2; ks++) {
            const int slot = ks * 4 + quad;   // 16B slot index of ko
            bf16x8 af[4], bfr[4];
#pragma unroll
            for (int mi = 0; mi < 4; mi++)
                af[mi] = *(const bf16x8*)&As[sw8(wm + mi * 16 + l15, slot)];
#pragma unroll
            for (int ni = 0; ni < 4; ni++)
                bfr[ni] = *(const bf16x8*)&Bs[sw8(wn + ni * 16 + l15, slot)];
#pragma unroll
            for (int mi = 0; mi < 4; mi++)
#pragma unroll
                for (int ni = 0; ni < 4; ni++)
                    acc[mi][ni] = __builtin_amdgcn_mfma_f32_16x16x32_bf16(
                        af[mi], bfr[ni], acc[mi][ni], 0, 0, 0);
        }
    }

    // epilogue: C/D layout col = lane&15, row = quad*4 + reg (m89/m91-verified)
#pragma unroll
    for (int ni = 0; ni < 4; ni++) {
        const int col = blockN + wn + ni * 16 + l15;
        const float bv = bias[col];
        if (SCATTER) {   // qkv scatter (shown split): h = col/192, r = col%192
            const int h = col / 192;
            const int r = col - h * 192;
            u16* C = (u16*)Cv;
#pragma unroll
            for (int mi = 0; mi < 4; mi++)
#pragma unroll
                for (int reg = 0; reg < 4; reg++) {
                    const int row = blockM + wm + mi * 16 + quad * 4 + reg;
                    const int b = row >> 11, t = row & 2047;
                    C[((size_t)((b * HH + h) * TT + t)) * 192 + r] =
                        f2bf(acc[mi][ni][reg] + bv);
                }
        } else {         // fp32 dense output
            float* C = (float*)Cv;
#pragma unroll
            for (int mi = 0; mi < 4; mi++)
#pragma unroll
                for (int reg = 0; reg < 4; reg++) {
                    const int row = blockM + wm + mi * 16 + quad * 4 + reg;
                    C[(size_t)row * N + col] = acc[mi][ni][reg] + bv;
                }
        }
    }
}

// ---------------- GEMM fallback (R15: fp32 inputs, register staging) --------------
template <int SCATTER, int QSLOT>
__global__ __launch_bounds__(256) void gemm_bt(const void* __restrict__ Av,
                                               const float* __restrict__ Bw,
                                               const float* __restrict__ bias,
                                               void* __restrict__ Cv,
                                               int K, int N) {
    __shared__ u16 As[128 * 64];   // 16 KB
    __shared__ u16 Bs[128 * 64];   // 16 KB

    const int tid  = threadIdx.x;
    const int lane = tid & 63;
    const int wave = tid >> 6;
    const int quad = lane >> 4;
    const int l15  = lane & 15;
    const int wm   = (wave >> 1) * 64;
    const int wn   = (wave & 1) * 64;
    const int blockM = blockIdx.y * 128;
    const int blockN = blockIdx.x * 128;

    floatx4 acc[4][4];
#pragma unroll
    for (int i = 0; i < 4; i++)
#pragma unroll
        for (int j = 0; j < 4; j++) acc[i][j] = (floatx4){0.f, 0.f, 0.f, 0.f};

    const int srow = lane >> 3;
    const int scol = (lane & 7) * 8;

    for (int k0 = 0; k0 < K; k0 += 64) {
        bf16x8 at[4], bt[4];
#pragma unroll
        for (int i = 0; i < 4; i++) {
            const int row = blockM + (i * 4 + wave) * 8 + srow;
            if (QSLOT) {
                const int b = row >> 11, t = row & 2047, h = k0 >> 6;
                at[i] = *(const bf16x8*)((const u16*)Av
                         + ((size_t)((b * HH + h) * TT + t)) * 192 + scol);
            } else {
                at[i] = cvt8((const float*)Av + (size_t)row * K + k0 + scol);
            }
        }
#pragma unroll
        for (int i = 0; i < 4; i++)
            bt[i] = cvt8(Bw + (size_t)(blockN + (i * 4 + wave) * 8 + srow) * K + k0 + scol);

        __syncthreads();
#pragma unroll
        for (int i = 0; i < 4; i++)
            *(bf16x8*)&As[sw8((i * 4 + wave) * 8 + srow, lane & 7)] = at[i];
#pragma unroll
        for (int i = 0; i < 4; i++)
            *(bf16x8*)&Bs[sw8((i * 4 + wave) * 8 + srow, lane & 7)] = bt[i];
        __syncthreads();

#pragma unroll
        for (int ks = 0; ks < 2; ks++) {
            const int slot = ks * 4 + quad;
            bf16x8 af[4], bfr[4];
#pragma unroll
            for (int mi = 0; mi < 4; mi++)
                af[mi] = *(const bf16x8*)&As[sw8(wm + mi * 16 + l15, slot)];
#pragma unroll
            for (int ni = 0; ni < 4; ni++)
                bfr[ni] = *(const bf16x8*)&Bs[sw8(wn + ni * 16 + l15, slot)];
#pragma unroll
            for (int mi = 0; mi < 4; mi++)
#pragma unroll
                for (int ni = 0; ni < 4; ni++)
                    acc[mi][ni] = __builtin_amdgcn_mfma_f32_16x16x32_bf16(
                        af[mi], bfr[ni], acc[mi][ni], 0, 0, 0);
        }
    }

#pragma unroll
    for (int ni = 0; ni < 4; ni++) {
        const int col = blockN + wn + ni * 16 + l15;
        const float bv = bias[col];
        if (SCATTER) {
            const int h = col / 192;
            const int r = col - h * 192;
            u16* C = (u16*)Cv;
#pragma unroll
            for (int mi = 0; mi < 4; mi++)
#pragma unroll
                for (int reg = 0; reg < 4; reg++) {
                    const int row = blockM + wm + mi * 16 + quad * 4 + reg;
                    const int b = row >> 11, t = row & 2047;
                    C[((size_t)((b * HH + h) * TT + t)) * 192 + r] =
                        f2bf(acc[mi][ni][reg] + bv);
                }
        } else {
            float* C = (float*)Cv;
#pragma unroll
            for (int mi = 0; mi < 4; mi++)
#pragma unroll
                for (int reg = 0; reg < 4; reg++) {
                    const int row = blockM + wm + mi * 16 + quad * 4 + reg;
                    C[(size_t)row * N + col] = acc[mi][ni][reg] + bv;
                }
        }
    }
}

// ---------------- Flash attention (R15: swapped QK^T, in-register P) --------------
__global__ __launch_bounds__(256) void attn_fwd(u16* __restrict__ qkv) {
    __shared__ u16 Ks[64 * 64];        // 8 KB  K-tile  [s][d]   (swizzled)
    __shared__ u16 Vts[64 * 64];       // 8 KB  V-tile transposed [d][s] (swizzled)

    const int tid  = threadIdx.x;
    const int lane = tid & 63;
    const int wave = tid >> 6;
    const int quad = lane >> 4;
    const int l15  = lane & 15;

    const int bh = blockIdx.y;
    const int t0 = blockIdx.x * 128;
    u16* Qg = qkv + (size_t)bh * TT * 192;

    bf16x8 qf[2][2];
#pragma unroll
    for (int qi = 0; qi < 2; qi++) {
        const int trow = t0 + wave * 32 + qi * 16 + l15;
#pragma unroll
        for (int ks = 0; ks < 2; ks++)
            qf[qi][ks] = *(const bf16x8*)(Qg + (size_t)trow * 192 + ks * 32 + quad * 8);
    }

    floatx4 o[2][4];
#pragma unroll
    for (int qi = 0; qi < 2; qi++)
#pragma unroll
        for (int di = 0; di < 4; di++) o[qi][di] = (floatx4){0.f, 0.f, 0.f, 0.f};
    float l_run[2] = {0.f, 0.f};

    const float cexp = 0.18033688f;    // log2(e)/8 : exp(s/8) = exp2(s*cexp)
    const int srow = lane >> 3;
    const int scol = (lane & 7) * 8;
    const int vs   = lane;
    const int vd0  = wave * 16;

    for (int s0 = 0; s0 < TT; s0 += 64) {
        bf16x8 kt[2];
#pragma unroll
        for (int i = 0; i < 2; i++)
            kt[i] = *(const bf16x8*)(Qg + (size_t)(s0 + (i * 4 + wave) * 8 + srow) * 192
                                     + 64 + scol);
        const u16* vp = Qg + (size_t)(s0 + vs) * 192 + 128 + vd0;
        bf16x8 v0 = *(const bf16x8*)vp;
        bf16x8 v1 = *(const bf16x8*)(vp + 8);

        __syncthreads();
#pragma unroll
        for (int i = 0; i < 2; i++)
            *(bf16x8*)&Ks[sw8((i * 4 + wave) * 8 + srow, lane & 7)] = kt[i];
        {
            const int vslot = vs >> 3, voff = vs & 7;
#pragma unroll
            for (int j = 0; j < 8; j++) {
                const int row = vd0 + j;
                Vts[row * 64 + (((vslot ^ (row & 7)) & 7) << 3) + voff] = (u16)v0[j];
            }
#pragma unroll
            for (int j = 0; j < 8; j++) {
                const int row = vd0 + 8 + j;
                Vts[row * 64 + (((vslot ^ (row & 7)) & 7) << 3) + voff] = (u16)v1[j];
            }
        }
        __syncthreads();

        floatx4 s_acc[4][2];
#pragma unroll
        for (int si = 0; si < 4; si++)
#pragma unroll
            for (int qi = 0; qi < 2; qi++) s_acc[si][qi] = (floatx4){0.f, 0.f, 0.f, 0.f};
#pragma unroll
        for (int ks = 0; ks < 2; ks++) {
            const int slot = ks * 4 + quad;
            bf16x8 kf[4];
#pragma unroll
            for (int si = 0; si < 4; si++)
                kf[si] = *(const bf16x8*)&Ks[sw8(si * 16 + l15, slot)];
#pragma unroll
            for (int si = 0; si < 4; si++)
#pragma unroll
                for (int qi = 0; qi < 2; qi++)
                    s_acc[si][qi] = __builtin_amdgcn_mfma_f32_16x16x32_bf16(
                        kf[si], qf[qi][ks], s_acc[si][qi], 0, 0, 0);
        }

        unsigned c[4][2][2];
        floatx4 rs[2] = {(floatx4){0.f,0.f,0.f,0.f}, (floatx4){0.f,0.f,0.f,0.f}};
#pragma unroll
        for (int si = 0; si < 4; si++)
#pragma unroll
            for (int qi = 0; qi < 2; qi++) {
                floatx4 p;
#pragma unroll
                for (int r = 0; r < 4; r++) p[r] = EXP2(s_acc[si][qi][r] * cexp);
                rs[qi] += p;
                c[si][qi][0] = pkbf(p[0], p[1]);
                c[si][qi][1] = pkbf(p[2], p[3]);
            }
#pragma unroll
        for (int qi = 0; qi < 2; qi++) {
            float v = rs[qi][0] + rs[qi][1] + rs[qi][2] + rs[qi][3];
            v += __shfl_xor(v, 16);
            v += __shfl_xor(v, 32);
            l_run[qi] += v;
        }

        union PF { bf16x8 v; unsigned u[4]; } pf[2][2];
#pragma unroll
        for (int qi = 0; qi < 2; qi++)
#pragma unroll
            for (int ks = 0; ks < 2; ks++)
#pragma unroll
                for (int h = 0; h < 2; h++) {
                    unsigned a = c[2 * ks][qi][h];
                    unsigned b = c[2 * ks + 1][qi][h];
                    pl32swap(a, b);
                    pl16swap(a, b);
                    pf[qi][ks].u[h]     = a;
                    pf[qi][ks].u[2 + h] = b;
                }

#pragma unroll
        for (int ks = 0; ks < 2; ks++) {
            const int slot = ks * 4 + quad;
            bf16x8 vf[4];
#pragma unroll
            for (int di = 0; di < 4; di++)
                vf[di] = *(const bf16x8*)&Vts[sw8(di * 16 + l15, slot)];
#pragma unroll
            for (int qi = 0; qi < 2; qi++)
#pragma unroll
                for (int di = 0; di < 4; di++)
                    o[qi][di] = __builtin_amdgcn_mfma_f32_16x16x32_bf16(
                        pf[qi][ks].v, vf[di], o[qi][di], 0, 0, 0);
        }
    }

#pragma unroll
    for (int qi = 0; qi < 2; qi++)
#pragma unroll
        for (int reg = 0; reg < 4; reg++) {
            const float lv = __shfl(l_run[qi], quad * 4 + reg);
            const float inv_l = 1.0f / lv;
            const int trow = t0 + wave * 32 + qi * 16 + quad * 4 + reg;
#pragma unroll
            for (int di = 0; di < 4; di++)
                Qg[(size_t)trow * 192 + di * 16 + l15] = f2bf(o[qi][di][reg] * inv_l);
        }
}

extern "C" void kernel_launch(void* const* d_in, const int* in_sizes, int n_in,
                              void* d_out, int out_size, void* d_ws, size_t ws_size,
                              hipStream_t stream) {
    (void)out_size;
    float* out = (float*)d_out;   // fp32 (R11-confirmed)

    const float *x = nullptr, *wq = nullptr, *bq = nullptr, *wo = nullptr, *bo = nullptr;
    int found = 0;
    for (int i = 0; i < n_in && i < 8; i++) {
        switch (in_sizes[i]) {
            case 8388608: x  = (const float*)d_in[i]; found |= 1;  break;
            case 3145728: wq = (const float*)d_in[i]; found |= 2;  break;
            case 3072:    bq = (const float*)d_in[i]; found |= 4;  break;
            case 1048576: wo = (const float*)d_in[i]; found |= 8;  break;
            case 1024:    bo = (const float*)d_in[i]; found |= 16; break;
        }
    }
    if (found != 31) {
        x  = (const float*)d_in[0]; wq = (const float*)d_in[1];
        bq = (const float*)d_in[2]; wo = (const float*)d_in[3];
        bo = (const float*)d_in[4];
    }

    u16* qkv = (u16*)d_ws;   // 48 MiB qkv ws (verified R6-R10)

    if (ws_size >= 75497472u) {   // 72 MiB: qkv(48) + xbf(16) + wqbf(6) + wobf(2)
        u16* xb  = qkv + 25165824;   // 48 MiB offset
        u16* wqb = qkv + 33554432;   // 64 MiB offset
        u16* wob = qkv + 36700160;   // 70 MiB offset

        cvt_all<<<2048, 256, 0, stream>>>(x, wq, wo, xb, wqb, wob);
        gemm_lds<1, 0><<<dim3(3 * CC / 128, BB * TT / 128), 256, 0, stream>>>(
            xb, wqb, bq, qkv, CC, 3 * CC);
        attn_fwd<<<dim3(TT / 128, BB * HH), 256, 0, stream>>>(qkv);
        gemm_lds<0, 1><<<dim3(CC / 128, BB * TT / 128), 256, 0, stream>>>(
            qkv, wob, bo, out, CC, CC);
    } else {                      // fallback: R15 path (no extra ws needed)
        gemm_bt<1, 0><<<dim3(3 * CC / 128, BB * TT / 128), 256, 0, stream>>>(
            x, wq, bq, qkv, CC, 3 * CC);
        attn_fwd<<<dim3(TT / 128, BB * HH), 256, 0, stream>>>(qkv);
        gemm_bt<0, 1><<<dim3(CC / 128, BB * TT / 128), 256, 0, stream>>>(
            qkv, wo, bo, out, CC, CC);
    }
}